// Round 3
// baseline (334.628 us; speedup 1.0000x reference)
//
#include <hip/hip_runtime.h>
#include <hip/hip_bf16.h>

typedef __attribute__((ext_vector_type(8))) short short8;
typedef __attribute__((ext_vector_type(4))) float f32x4;
typedef unsigned int uint;
typedef unsigned short ushort;

constexpr int BATCH = 4;
constexpr int CH    = 256;
constexpr int N     = 4096;   // 64*64
constexpr int DVC   = 768;
constexpr int CIN   = 1024;   // CH + DVC
constexpr int KC    = 512;    // 2*CH
constexpr int PBS   = 5 * 1024 * 1024;  // P per-batch stride (elements); (nfg+127)*(nbg+127) <= 4.46M

// ---------------- workspace layout (bytes), total 82 MB ----------------
constexpr size_t OFF_M    = 0;                       // 16384 f32
constexpr size_t OFF_INV  = 64ull << 10;             // 16384 f32 (compact, per fg slot)
constexpr size_t OFF_VIS  = 128ull << 10;            // 16384 f32
constexpr size_t OFF_MAXV = 192ull << 10;            // 1 f32
constexpr size_t OFF_CNT  = 196ull << 10;            // 16 ints {nfg,nfgp,nbg,nbgp} x4
constexpr size_t OFF_FGI  = 256ull << 10;            // 16384 int
constexpr size_t OFF_BGI  = 320ull << 10;            // 16384 int
constexpr size_t OFF_P2S  = 384ull << 10;            // 16384 int
constexpr size_t OFF_KMC  = 448ull << 10;            // 16384 f32
constexpr size_t OFF_PART = 512ull << 10;            // 8*16384 f32 = 512KB
constexpr size_t OFF_KWB  = 1ull << 20;              // 512KB bf16
constexpr size_t OFF_FWB  = OFF_KWB + (512ull << 10);// 256KB bf16
constexpr size_t OFF_XT   = 2ull << 20;              // [b][n][256] bf16 = 8MB
constexpr size_t OFF_DVTT = 10ull << 20;             // [b][n][768] bf16 = 24MB (dead after feats)
constexpr size_t OFF_QC   = OFF_DVTT;                //   [b][qi][256] bf16 = 8MB
constexpr size_t OFF_KCC  = OFF_DVTT + (8ull << 20); //   [b][ki][256] bf16 = 8MB
constexpr size_t OFF_XC   = OFF_DVTT + (16ull << 20);//   [b][c][4096] bf16 = 8MB
constexpr size_t OFF_AFT  = 34ull << 20;             // [b][n][256] bf16 = 8MB (dense, zero+scatter)
constexpr size_t OFF_P    = 42ull << 20;             // compact P bf16, 4 x PBS = 40MB
constexpr size_t OFF_FNT  = OFF_P;                   // [b][n][256] f32 = 16MB overlay (dead pre-score)

// ---------------- helpers ----------------
__device__ __forceinline__ ushort f2bf(float f) {
    __hip_bfloat16 h = __float2bfloat16(f);
    return __builtin_bit_cast(ushort, h);
}
__device__ __forceinline__ float bf2f(ushort u) {
    uint v = (uint)u << 16;
    return __builtin_bit_cast(float, v);
}

typedef const __attribute__((address_space(1))) uint* gptr_t;
typedef __attribute__((address_space(3))) uint* lptr_t;
__device__ __forceinline__ void gload_lds16(const void* g, void* l) {
    __builtin_amdgcn_global_load_lds((gptr_t)g, (lptr_t)l, 16, 0, 0);
}

// ---------------- shared GEMM mainloop ----------------
// C[m][n] = sum_k A[m][k]*B'[n][k]; bf16; tiles BMx64 / BNx64 linear in LDS.
// B switches source at k=kend0.
template<int WM, int WN>
__device__ __forceinline__ void gemm_core(
    const ushort* __restrict__ A0, int lda, int m0,
    const ushort* __restrict__ B0, int ldb0, int kend0,
    const ushort* __restrict__ B1, int ldb1,
    int n0, int K,
    ushort* AsL, ushort* BsL, f32x4 acc[4][4])
{
    constexpr int NW = WM * WN, BM = WM * 64, BN = WN * 64;
    const int t = threadIdx.x, lane = t & 63, wid = t >> 6;
    const int wm = (wid / WN) * 64, wn = (wid % WN) * 64;

    for (int k0 = 0; k0 < K; k0 += 64) {
        #pragma unroll
        for (int c = wid; c < BM / 8; c += NW) {
            const ushort* g = A0 + (size_t)(m0 + c * 8 + (lane >> 3)) * lda + (k0 + (lane & 7) * 8);
            gload_lds16(g, AsL + c * 512);
        }
        const ushort* Bsrc = (k0 < kend0) ? B0 : B1;
        const int ldb = (k0 < kend0) ? ldb0 : ldb1;
        const int kc  = (k0 < kend0) ? k0 : (k0 - kend0);
        #pragma unroll
        for (int c = wid; c < BN / 8; c += NW) {
            const ushort* g = Bsrc + (size_t)(n0 + c * 8 + (lane >> 3)) * ldb + (kc + (lane & 7) * 8);
            gload_lds16(g, BsL + c * 512);
        }
        __syncthreads();

        const int ra = wm + (lane & 15), rb = wn + (lane & 15), ko = (lane >> 4) * 8;
        #pragma unroll
        for (int kk = 0; kk < 64; kk += 32) {
            short8 a[4], b[4];
            #pragma unroll
            for (int i = 0; i < 4; i++) a[i] = *(const short8*)(AsL + (ra + i * 16) * 64 + kk + ko);
            #pragma unroll
            for (int j = 0; j < 4; j++) b[j] = *(const short8*)(BsL + (rb + j * 16) * 64 + kk + ko);
            #pragma unroll
            for (int i = 0; i < 4; i++)
                #pragma unroll
                for (int j = 0; j < 4; j++)
                    acc[i][j] = __builtin_amdgcn_mfma_f32_16x16x32_bf16(a[i], b[j], acc[i][j], 0, 0, 0);
        }
        __syncthreads();
    }
}

__device__ __forceinline__ void zero_acc(f32x4 acc[4][4]) {
    f32x4 z = {0.f, 0.f, 0.f, 0.f};
    #pragma unroll
    for (int i = 0; i < 4; i++)
        #pragma unroll
        for (int j = 0; j < 4; j++) acc[i][j] = z;
}

// ---------------- mask + compaction ----------------
__global__ void k_maskpool(const float* __restrict__ mask, float* __restrict__ m)
{
    int idx = blockIdx.x * 256 + threadIdx.x;
    int b = idx >> 12, p = idx & 4095;
    int y = p >> 6, x = p & 63;
    const float* base = mask + (size_t)b * 512 * 512 + (y * 8) * 512 + x * 8;
    float mx = 0.f;
    for (int dy = 0; dy < 8; dy++) {
        #pragma unroll
        for (int dx = 0; dx < 8; dx++) mx = fmaxf(mx, base[dy * 512 + dx]);
    }
    m[idx] = (mx > 0.f) ? 1.f : 0.f;
}

// one block per batch: prefix-scan the fg mask into compact index lists
__global__ __launch_bounds__(256) void k_scan(
    const float* __restrict__ m, int* __restrict__ fgi, int* __restrict__ bgi,
    int* __restrict__ counts, float* __restrict__ kmc, int* __restrict__ p2s)
{
    const int b = blockIdx.x, t = threadIdx.x;
    const float* mb = m + (size_t)b * N;
    __shared__ int sfg[256], sbg[256];
    bool isf[16];
    int cf = 0, cb_ = 0;
    #pragma unroll
    for (int j = 0; j < 16; j++) {
        bool f = mb[t * 16 + j] != 0.f;
        isf[j] = f; cf += f ? 1 : 0; cb_ += f ? 0 : 1;
    }
    sfg[t] = cf; sbg[t] = cb_;
    __syncthreads();
    for (int off = 1; off < 256; off <<= 1) {
        int vf = (t >= off) ? sfg[t - off] : 0;
        int vb = (t >= off) ? sbg[t - off] : 0;
        __syncthreads();
        sfg[t] += vf; sbg[t] += vb;
        __syncthreads();
    }
    int basef = sfg[t] - cf, baseb = sbg[t] - cb_;
    int nfg = sfg[255], nbg = sbg[255];
    #pragma unroll
    for (int j = 0; j < 16; j++) {
        int p = t * 16 + j;
        if (isf[j]) { fgi[b * N + basef] = p; p2s[b * N + p] = basef | (1 << 30); basef++; }
        else        { bgi[b * N + baseb] = p; p2s[b * N + p] = baseb; baseb++; }
    }
    if (t == 0) {
        counts[b * 4 + 0] = nfg;
        counts[b * 4 + 1] = (nfg + 127) & ~127;
        counts[b * 4 + 2] = nbg;
        counts[b * 4 + 3] = (nbg + 127) & ~127;
    }
    for (int j = t; j < N; j += 256) kmc[b * N + j] = (j < nbg) ? 1.f : 0.f;
}

// zero pad rows of Qc/Kc (runs AFTER feats since Qc/Kc overlay dvtT)
__global__ void k_padzero(const int* __restrict__ counts,
                          ushort* __restrict__ Qc, ushort* __restrict__ Kc)
{
    int b = blockIdx.x, t = threadIdx.x;
    int nfg = counts[b * 4], nfgp = counts[b * 4 + 1];
    int nbg = counts[b * 4 + 2], nbgp = counts[b * 4 + 3];
    for (int i = t; i < (nfgp - nfg) * CH; i += 256) Qc[((size_t)b * N + nfg) * CH + i] = 0;
    for (int i = t; i < (nbgp - nbg) * CH; i += 256) Kc[((size_t)b * N + nbg) * CH + i] = 0;
}

// zero AFt (dense) + vis
__global__ void k_zero(uint4* __restrict__ AFt4, uint4* __restrict__ vis4)
{
    int idx = blockIdx.x * 256 + threadIdx.x;
    uint4 z = {0, 0, 0, 0};
    if (idx < BATCH * N * CH * 2 / 16) AFt4[idx] = z;
    else                               vis4[idx - BATCH * N * CH * 2 / 16] = z;
}

// ---------------- weight/feature prep ----------------
__global__ void k_wconv(const float* __restrict__ Kw, const float* __restrict__ fw,
                        ushort* __restrict__ Kwb, ushort* __restrict__ fwb)
{
    int i = blockIdx.x * 256 + threadIdx.x;
    if (i < CH * CIN) Kwb[i] = f2bf(Kw[i]);
    else              fwb[i - CH * CIN] = f2bf(fw[i - CH * CIN]);
}

// transpose f32 [b][C][4096] -> bf16 [b][4096][C]
__global__ __launch_bounds__(256) void k_tr(const float* __restrict__ src,
                                            ushort* __restrict__ dst, int C)
{
    __shared__ float Ls[64][65];
    const int ci0 = blockIdx.x * 64, n0 = blockIdx.y * 64, b = blockIdx.z;
    const float* s = src + (size_t)b * C * 4096;
    const int t = threadIdx.x;
    #pragma unroll
    for (int it = 0; it < 4; it++) {
        int f4 = it * 256 + t;
        int r = f4 >> 4, c4 = f4 & 15;
        float4 v = *(const float4*)(s + (size_t)(ci0 + r) * 4096 + n0 + c4 * 4);
        Ls[r][c4 * 4 + 0] = v.x; Ls[r][c4 * 4 + 1] = v.y;
        Ls[r][c4 * 4 + 2] = v.z; Ls[r][c4 * 4 + 3] = v.w;
    }
    __syncthreads();
    ushort* d = dst + (size_t)b * 4096 * C;
    #pragma unroll
    for (int it = 0; it < 8; it++) {
        int p = it * 256 + t;
        int rn = p >> 5, cc2 = p & 31;
        uint val = (uint)f2bf(Ls[cc2 * 2][rn]) | ((uint)f2bf(Ls[cc2 * 2 + 1][rn]) << 16);
        *(uint*)(d + (size_t)(n0 + rn) * C + ci0 + cc2 * 2) = val;
    }
}

// gather V compact: xc[b][c][j] = bf16(x[b][c][bgi[j]]) (0 for pads)
__global__ void k_vgather(const float* __restrict__ x, const int* __restrict__ bgi,
                          const int* __restrict__ counts, ushort* __restrict__ xc)
{
    int bc = blockIdx.x;
    int b = bc >> 8, c = bc & 255;
    int nbg = counts[b * 4 + 2], nbgp = counts[b * 4 + 3];
    const float* xr = x + ((size_t)b * CH + c) * N;
    const int* bi = bgi + (size_t)b * N;
    ushort* dst = xc + ((size_t)b * CH + c) * N;
    for (int j = threadIdx.x; j < nbgp; j += 256)
        dst[j] = (j < nbg) ? f2bf(xr[bi[j]]) : (ushort)0;
}

// ---------------- feats GEMM (dense) ----------------
__global__ __launch_bounds__(128) void k_feats(
    const ushort* __restrict__ Kwb, const ushort* __restrict__ xT,
    const ushort* __restrict__ dvtT, const float* __restrict__ Kb,
    float* __restrict__ FnT)
{
    __shared__ ushort SH[(64 + 128) * 64];
    const int b = blockIdx.z;
    const int n0 = blockIdx.x * 128, m0 = blockIdx.y * 64;
    const int lane = threadIdx.x & 63, wid = threadIdx.x >> 6;
    const int wn = (wid & 1) * 64;
    f32x4 acc[4][4]; zero_acc(acc);
    gemm_core<1, 2>(Kwb, CIN, m0,
                    xT + (size_t)b * N * CH, CH, CH,
                    dvtT + (size_t)b * N * DVC, DVC,
                    n0, CIN, SH, SH + 64 * 64, acc);
    float* Fb = FnT + (size_t)b * N * CH;
    #pragma unroll
    for (int i = 0; i < 4; i++) {
        int mbase = m0 + i * 16 + ((lane >> 4) * 4);
        float4 bias = *(const float4*)(Kb + mbase);
        #pragma unroll
        for (int j = 0; j < 4; j++) {
            int n = n0 + wn + j * 16 + (lane & 15);
            float4 o;
            o.x = acc[i][j][0] + bias.x; o.y = acc[i][j][1] + bias.y;
            o.z = acc[i][j][2] + bias.z; o.w = acc[i][j][3] + bias.w;
            *(float4*)(Fb + (size_t)n * CH + mbase) = o;
        }
    }
}

// normalize + scatter into compact Qc / Kc
__global__ __launch_bounds__(256) void k_normalize(
    const float* __restrict__ FnT, const int* __restrict__ p2s,
    ushort* __restrict__ Qc, ushort* __restrict__ Kc)
{
    const int t = threadIdx.x, lane = t & 63, wid = t >> 6;
    const int g = blockIdx.x * 4 + wid;   // b*N + p
    const int b = g >> 12;
    const float* src = FnT + (size_t)g * CH;
    float4 v = *(const float4*)(src + lane * 4);
    float s = v.x * v.x + v.y * v.y + v.z * v.z + v.w * v.w;
    #pragma unroll
    for (int mm = 1; mm < 64; mm <<= 1) s += __shfl_xor(s, mm);
    float inv_ = 1.f / (sqrtf(s) + 1e-8f);
    int sl = p2s[g];
    ushort* dst = (sl & (1 << 30)) ? Qc : Kc;
    int slot = sl & 0x3FFFFFFF;
    ushort4 o = { f2bf(v.x * inv_), f2bf(v.y * inv_), f2bf(v.z * inv_), f2bf(v.w * inv_) };
    *(ushort4*)(dst + ((size_t)b * N + slot) * CH + lane * 4) = o;
}

// ---------------- score GEMM (compact): P[qi][ki] = kmc[ki]*exp(20*dot-20) ----------------
__global__ __launch_bounds__(256) void k_score(
    const ushort* __restrict__ Qc, const ushort* __restrict__ Kc,
    const float* __restrict__ kmc, const int* __restrict__ counts,
    ushort* __restrict__ P)
{
    const int b = blockIdx.z;
    const int nfgp = counts[b * 4 + 1], nbgp = counts[b * 4 + 3];
    const int m0 = blockIdx.y * 128, n0 = blockIdx.x * 128;
    if (m0 >= nfgp || n0 >= nbgp) return;
    __shared__ ushort SH[(128 + 128) * 64];
    const int t = threadIdx.x, lane = t & 63, wid = t >> 6;
    const int wm = (wid >> 1) * 64, wn = (wid & 1) * 64;
    const ushort* Qb = Qc + (size_t)b * N * CH;
    const ushort* Kb_ = Kc + (size_t)b * N * CH;
    f32x4 acc[4][4]; zero_acc(acc);
    gemm_core<2, 2>(Qb, CH, m0, Kb_, CH, CH, Kb_, CH, n0, CH, SH, SH + 128 * 64, acc);

    float km[4];
    #pragma unroll
    for (int j = 0; j < 4; j++) km[j] = kmc[(size_t)b * N + n0 + wn + j * 16 + (lane & 15)];

    ushort* Cs = SH;
    #pragma unroll
    for (int i = 0; i < 4; i++) {
        int rbase = wm + i * 16 + ((lane >> 4) * 4);
        #pragma unroll
        for (int j = 0; j < 4; j++) {
            int cl = wn + j * 16 + (lane & 15);
            #pragma unroll
            for (int r = 0; r < 4; r++) {
                float p = km[j] * __expf(20.f * acc[i][j][r] - 20.f);
                Cs[(rbase + r) * 128 + cl] = f2bf(p);
            }
        }
    }
    __syncthreads();
    ushort* Pb = P + (size_t)b * PBS;
    #pragma unroll
    for (int it = 0; it < 8; it++) {
        int v8 = it * 256 + t;
        int row = v8 >> 4, c8 = (v8 & 15) * 8;
        *(uint4*)(Pb + (size_t)(m0 + row) * nbgp + n0 + c8) = *(const uint4*)(Cs + row * 128 + c8);
    }
}

// rowsum -> inv[qi] (compact)
__global__ __launch_bounds__(256) void k_rowsum(
    const ushort* __restrict__ P, const int* __restrict__ counts,
    float* __restrict__ inv)
{
    const int t = threadIdx.x, lane = t & 63, wid = t >> 6;
    const int g = blockIdx.x * 4 + wid;
    const int b = g >> 12, qi = g & 4095;
    const int nfgp = counts[b * 4 + 1], nbgp = counts[b * 4 + 3];
    if (qi >= nfgp) return;
    const ushort* row = P + (size_t)b * PBS + (size_t)qi * nbgp;
    float s = 0.f;
    for (int it = 0; it < 8; it++) {
        int base = it * 512 + lane * 8;
        if (base < nbgp) {
            uint4 v = *(const uint4*)(row + base);
            const ushort* u = (const ushort*)&v;
            #pragma unroll
            for (int e = 0; e < 8; e++) s += bf2f(u[e]);
        }
    }
    #pragma unroll
    for (int mm = 1; mm < 64; mm <<= 1) s += __shfl_xor(s, mm);
    if (lane == 0) inv[g] = (s > 0.f) ? 1.f / s : 0.f;
}

// ---------------- PV GEMM (compact): AF[c][qi] = sum_ki xc[c][ki]*P[qi][ki]; scatter ----------------
__global__ __launch_bounds__(128) void k_att_fore(
    const ushort* __restrict__ xc, const ushort* __restrict__ P,
    const float* __restrict__ inv, const int* __restrict__ fgi,
    const int* __restrict__ counts, ushort* __restrict__ AFt)
{
    const int b = blockIdx.z;
    const int nfg = counts[b * 4], nfgp = counts[b * 4 + 1], nbgp = counts[b * 4 + 3];
    const int n0 = blockIdx.x * 128;   // qi tile
    const int m0 = blockIdx.y * 64;    // c tile
    if (n0 >= nfgp) return;
    __shared__ ushort SH[(64 + 128) * 64];
    const int lane = threadIdx.x & 63, wid = threadIdx.x >> 6;
    const int wn = (wid & 1) * 64;
    const ushort* Pb = P + (size_t)b * PBS;
    f32x4 acc[4][4]; zero_acc(acc);
    gemm_core<1, 2>(xc + (size_t)b * CH * N, N, m0,
                    Pb, nbgp, 1 << 30, Pb, nbgp,
                    n0, nbgp, SH, SH + 64 * 64, acc);
    const float* invb = inv + (size_t)b * N;
    const int* fb = fgi + (size_t)b * N;
    ushort* Ab = AFt + (size_t)b * N * CH;
    #pragma unroll
    for (int j = 0; j < 4; j++) {
        int qi = n0 + wn + j * 16 + (lane & 15);
        if (qi < nfg) {
            int q = fb[qi];
            float iq = invb[qi];
            #pragma unroll
            for (int i = 0; i < 4; i++) {
                int mbase = m0 + i * 16 + ((lane >> 4) * 4);
                ushort4 o = { f2bf(acc[i][j][0] * iq), f2bf(acc[i][j][1] * iq),
                              f2bf(acc[i][j][2] * iq), f2bf(acc[i][j][3] * iq) };
                *(ushort4*)(Ab + (size_t)q * CH + mbase) = o;
            }
        }
    }
}

// ---------------- fused GEMM + blend (dense) ----------------
__global__ __launch_bounds__(128) void k_fused(
    const ushort* __restrict__ fwb, const ushort* __restrict__ AFt,
    const ushort* __restrict__ xT, const float* __restrict__ x,
    const float* __restrict__ m_, float* __restrict__ out)
{
    __shared__ ushort SH[(64 + 128) * 64];
    const int b = blockIdx.z;
    const int n0 = blockIdx.x * 128, m0 = blockIdx.y * 64;
    const int lane = threadIdx.x & 63, wid = threadIdx.x >> 6;
    const int wn = (wid & 1) * 64;
    f32x4 acc[4][4]; zero_acc(acc);
    gemm_core<1, 2>(fwb, KC, m0,
                    AFt + (size_t)b * N * CH, CH, CH,
                    xT + (size_t)b * N * CH, CH,
                    n0, KC, SH, SH + 64 * 64, acc);
    const float* mb = m_ + (size_t)b * N;
    const float* xc_ = x + (size_t)b * CH * N;
    float* ob = out + (size_t)b * CH * N;
    #pragma unroll
    for (int j = 0; j < 4; j++) {
        int n = n0 + wn + j * 16 + (lane & 15);
        float mv = mb[n];
        #pragma unroll
        for (int i = 0; i < 4; i++) {
            int mbase = m0 + i * 16 + ((lane >> 4) * 4);
            #pragma unroll
            for (int r = 0; r < 4; r++) {
                int c = mbase + r;
                ob[(size_t)c * N + n] = (mv != 0.f) ? acc[i][j][r] : xc_[(size_t)c * N + n];
            }
        }
    }
}

// ---------------- colsum (compact) + vis ----------------
__global__ void k_colsum_part(const ushort* __restrict__ P, const float* __restrict__ inv,
                              const int* __restrict__ counts, float* __restrict__ part)
{
    int g = blockIdx.x * 256 + threadIdx.x;
    int b = g >> 12, ki = g & 4095;
    int qc = blockIdx.y;
    int nfg = counts[b * 4], nbgp = counts[b * 4 + 3];
    float s = 0.f;
    if (ki < nbgp) {
        int q0 = qc * 512, q1 = min(q0 + 512, nfg);
        const ushort* base = P + (size_t)b * PBS + (size_t)q0 * nbgp + ki;
        const float* ib = inv + (size_t)b * N + q0;
        for (int q = q0; q < q1; q++) {
            s += bf2f(*base) * ib[q - q0];
            base += nbgp;
        }
    }
    part[(size_t)qc * BATCH * N + g] = s;
}

__global__ void k_colsum_final(const float* __restrict__ part, const int* __restrict__ bgi,
                               const int* __restrict__ counts, float* __restrict__ vis)
{
    int g = blockIdx.x * 256 + threadIdx.x;
    int b = g >> 12, ki = g & 4095;
    if (ki >= counts[b * 4 + 2]) return;
    float s = 0.f;
    #pragma unroll
    for (int j = 0; j < 8; j++) s += part[(size_t)j * BATCH * N + g];
    vis[(size_t)b * N + bgi[(size_t)b * N + ki]] = s;
}

__global__ void k_vismax(const float* __restrict__ vis, float* __restrict__ maxv)
{
    __shared__ float red[256];
    int t = threadIdx.x;
    float mx = 0.f;
    for (int i = t; i < BATCH * N; i += 256) mx = fmaxf(mx, vis[i]);
    red[t] = mx; __syncthreads();
    for (int s = 128; s > 0; s >>= 1) { if (t < s) red[t] = fmaxf(red[t], red[t + s]); __syncthreads(); }
    if (t == 0) maxv[0] = red[0];
}

__global__ void k_attmask(const float* __restrict__ vis, const float* __restrict__ maxv,
                          float* __restrict__ amask)
{
    int idx = blockIdx.x * 256 + threadIdx.x;
    int b = idx >> 18;
    int r = idx & 262143;
    int Y = r >> 9, X = r & 511;
    amask[idx] = vis[(size_t)b * N + (Y >> 3) * 64 + (X >> 3)] / maxv[0];
}

// ---------------- launch ----------------
extern "C" void kernel_launch(void* const* d_in, const int* in_sizes, int n_in,
                              void* d_out, int out_size, void* d_ws, size_t ws_size,
                              hipStream_t stream)
{
    const float* x    = (const float*)d_in[0];
    const float* mask = (const float*)d_in[1];
    const float* dvt  = (const float*)d_in[2];
    const float* Kw   = (const float*)d_in[3];
    const float* Kb   = (const float*)d_in[4];
    const float* fw   = (const float*)d_in[5];
    float* out = (float*)d_out;

    char* ws = (char*)d_ws;
    float*  m    = (float*)(ws + OFF_M);
    float*  inv  = (float*)(ws + OFF_INV);
    float*  vis  = (float*)(ws + OFF_VIS);
    float*  maxv = (float*)(ws + OFF_MAXV);
    int*    cnt  = (int*)  (ws + OFF_CNT);
    int*    fgi  = (int*)  (ws + OFF_FGI);
    int*    bgi  = (int*)  (ws + OFF_BGI);
    int*    p2s  = (int*)  (ws + OFF_P2S);
    float*  kmc  = (float*)(ws + OFF_KMC);
    float*  part = (float*)(ws + OFF_PART);
    ushort* Kwb  = (ushort*)(ws + OFF_KWB);
    ushort* fwb  = (ushort*)(ws + OFF_FWB);
    ushort* xT   = (ushort*)(ws + OFF_XT);
    ushort* dvtT = (ushort*)(ws + OFF_DVTT);
    ushort* Qc   = (ushort*)(ws + OFF_QC);
    ushort* Kcc  = (ushort*)(ws + OFF_KCC);
    ushort* xc   = (ushort*)(ws + OFF_XC);
    ushort* AFt  = (ushort*)(ws + OFF_AFT);
    ushort* P    = (ushort*)(ws + OFF_P);
    float*  FnT  = (float*)(ws + OFF_FNT);

    k_maskpool   <<<dim3(BATCH * N / 256), 256, 0, stream>>>(mask, m);
    k_scan       <<<dim3(BATCH), 256, 0, stream>>>(m, fgi, bgi, cnt, kmc, p2s);
    k_wconv      <<<dim3((CH * CIN + CH * KC) / 256), 256, 0, stream>>>(Kw, fw, Kwb, fwb);
    k_tr         <<<dim3(CH / 64, 64, BATCH), 256, 0, stream>>>(x, xT, CH);
    k_tr         <<<dim3(DVC / 64, 64, BATCH), 256, 0, stream>>>(dvt, dvtT, DVC);
    k_feats      <<<dim3(N / 128, CH / 64, BATCH), 128, 0, stream>>>(Kwb, xT, dvtT, Kb, FnT);
    k_padzero    <<<dim3(BATCH), 256, 0, stream>>>(cnt, Qc, Kcc);
    k_zero       <<<dim3((BATCH * N * CH * 2 / 16 + BATCH * N * 4 / 16) / 256), 256, 0, stream>>>(
                     (uint4*)AFt, (uint4*)vis);
    k_normalize  <<<dim3(BATCH * N / 4), 256, 0, stream>>>(FnT, p2s, Qc, Kcc);
    k_vgather    <<<dim3(BATCH * CH), 256, 0, stream>>>(x, bgi, cnt, xc);
    k_score      <<<dim3(N / 128, N / 128, BATCH), 256, 0, stream>>>(Qc, Kcc, kmc, cnt, P);
    k_rowsum     <<<dim3(BATCH * N / 4), 256, 0, stream>>>(P, cnt, inv);
    k_att_fore   <<<dim3(N / 128, CH / 64, BATCH), 128, 0, stream>>>(xc, P, inv, fgi, cnt, AFt);
    k_colsum_part<<<dim3(BATCH * N / 256, 8), 256, 0, stream>>>(P, inv, cnt, part);
    k_colsum_final<<<dim3(BATCH * N / 256), 256, 0, stream>>>(part, bgi, cnt, vis);
    k_vismax     <<<dim3(1), 256, 0, stream>>>(vis, maxv);
    k_fused      <<<dim3(N / 128, CH / 64, BATCH), 128, 0, stream>>>(fwb, AFt, xT, x, m, out);
    k_attmask    <<<dim3(BATCH * 512 * 512 / 256), 256, 0, stream>>>(vis, maxv, out + (size_t)BATCH * CH * N);
}

// Round 4
// 217.240 us; speedup vs baseline: 1.5404x; 1.5404x over previous
//
#include <hip/hip_runtime.h>
#include <hip/hip_bf16.h>

typedef __attribute__((ext_vector_type(8))) short short8;
typedef __attribute__((ext_vector_type(4))) float f32x4;
typedef unsigned int uint;
typedef unsigned short ushort;

constexpr int BATCH = 4;
constexpr int CH    = 256;
constexpr int N     = 4096;   // 64*64
constexpr int DVC   = 768;
constexpr int CIN   = 1024;   // CH + DVC
constexpr int KC    = 512;    // 2*CH
constexpr int PBS   = 5 * 1024 * 1024;  // P per-batch stride (elements)
constexpr int QCH   = 32;     // colsum q-chunks

// ---------------- workspace layout (bytes), total 84 MB ----------------
constexpr size_t OFF_M    = 0;                       // 16384 f32
constexpr size_t OFF_INV  = 64ull << 10;             // 16384 f32 (compact, per fg slot)
constexpr size_t OFF_VIS  = 128ull << 10;            // 16384 f32
constexpr size_t OFF_MAXV = 192ull << 10;            // 1 f32
constexpr size_t OFF_CNT  = 196ull << 10;            // 16 ints {nfg,nfgp,nbg,nbgp} x4
constexpr size_t OFF_FGI  = 256ull << 10;            // 16384 int
constexpr size_t OFF_BGI  = 320ull << 10;            // 16384 int
constexpr size_t OFF_P2S  = 384ull << 10;            // 16384 int
constexpr size_t OFF_KMC  = 448ull << 10;            // 16384 f32
constexpr size_t OFF_PART = 512ull << 10;            // QCH*16384 f32 = 2MB
constexpr size_t OFF_KWB  = 3ull << 20;              // 512KB bf16
constexpr size_t OFF_FWB  = OFF_KWB + (512ull << 10);// 256KB bf16
constexpr size_t OFF_XT   = 4ull << 20;              // [b][n][256] bf16 = 8MB
constexpr size_t OFF_DVTT = 12ull << 20;             // [b][n][768] bf16 = 24MB (dead after feats)
constexpr size_t OFF_QC   = OFF_DVTT;                //   [b][qi][256] bf16 = 8MB
constexpr size_t OFF_KCC  = OFF_DVTT + (8ull << 20); //   [b][ki][256] bf16 = 8MB
constexpr size_t OFF_XC   = OFF_DVTT + (16ull << 20);//   [b][c][4096] bf16 = 8MB
constexpr size_t OFF_AFT  = 36ull << 20;             // [b][n][256] bf16 = 8MB (dense, zero+scatter)
constexpr size_t OFF_P    = 44ull << 20;             // compact P bf16, 4 x PBS = 40MB
constexpr size_t OFF_FNT  = OFF_P;                   // [b][n][256] f32 = 16MB overlay (dead pre-score)

// ---------------- helpers ----------------
__device__ __forceinline__ ushort f2bf(float f) {
    __hip_bfloat16 h = __float2bfloat16(f);
    return __builtin_bit_cast(ushort, h);
}
__device__ __forceinline__ float bf2f(ushort u) {
    uint v = (uint)u << 16;
    return __builtin_bit_cast(float, v);
}

typedef const __attribute__((address_space(1))) uint* gptr_t;
typedef __attribute__((address_space(3))) uint* lptr_t;
__device__ __forceinline__ void gload_lds16(const void* g, void* l) {
    __builtin_amdgcn_global_load_lds((gptr_t)g, (lptr_t)l, 16, 0, 0);
}

// ---------------- shared GEMM mainloop ----------------
template<int WM, int WN>
__device__ __forceinline__ void gemm_core(
    const ushort* __restrict__ A0, int lda, int m0,
    const ushort* __restrict__ B0, int ldb0, int kend0,
    const ushort* __restrict__ B1, int ldb1,
    int n0, int K,
    ushort* AsL, ushort* BsL, f32x4 acc[4][4])
{
    constexpr int NW = WM * WN, BM = WM * 64, BN = WN * 64;
    const int t = threadIdx.x, lane = t & 63, wid = t >> 6;
    const int wm = (wid / WN) * 64, wn = (wid % WN) * 64;

    for (int k0 = 0; k0 < K; k0 += 64) {
        #pragma unroll
        for (int c = wid; c < BM / 8; c += NW) {
            const ushort* g = A0 + (size_t)(m0 + c * 8 + (lane >> 3)) * lda + (k0 + (lane & 7) * 8);
            gload_lds16(g, AsL + c * 512);
        }
        const ushort* Bsrc = (k0 < kend0) ? B0 : B1;
        const int ldb = (k0 < kend0) ? ldb0 : ldb1;
        const int kc  = (k0 < kend0) ? k0 : (k0 - kend0);
        #pragma unroll
        for (int c = wid; c < BN / 8; c += NW) {
            const ushort* g = Bsrc + (size_t)(n0 + c * 8 + (lane >> 3)) * ldb + (kc + (lane & 7) * 8);
            gload_lds16(g, BsL + c * 512);
        }
        __syncthreads();

        const int ra = wm + (lane & 15), rb = wn + (lane & 15), ko = (lane >> 4) * 8;
        #pragma unroll
        for (int kk = 0; kk < 64; kk += 32) {
            short8 a[4], b[4];
            #pragma unroll
            for (int i = 0; i < 4; i++) a[i] = *(const short8*)(AsL + (ra + i * 16) * 64 + kk + ko);
            #pragma unroll
            for (int j = 0; j < 4; j++) b[j] = *(const short8*)(BsL + (rb + j * 16) * 64 + kk + ko);
            #pragma unroll
            for (int i = 0; i < 4; i++)
                #pragma unroll
                for (int j = 0; j < 4; j++)
                    acc[i][j] = __builtin_amdgcn_mfma_f32_16x16x32_bf16(a[i], b[j], acc[i][j], 0, 0, 0);
        }
        __syncthreads();
    }
}

__device__ __forceinline__ void zero_acc(f32x4 acc[4][4]) {
    f32x4 z = {0.f, 0.f, 0.f, 0.f};
    #pragma unroll
    for (int i = 0; i < 4; i++)
        #pragma unroll
        for (int j = 0; j < 4; j++) acc[i][j] = z;
}

// ---------------- mask + compaction ----------------
__global__ void k_maskpool(const float* __restrict__ mask, float* __restrict__ m)
{
    int idx = blockIdx.x * 256 + threadIdx.x;
    int b = idx >> 12, p = idx & 4095;
    int y = p >> 6, x = p & 63;
    const float* base = mask + (size_t)b * 512 * 512 + (y * 8) * 512 + x * 8;
    float mx = 0.f;
    for (int dy = 0; dy < 8; dy++) {
        #pragma unroll
        for (int dx = 0; dx < 8; dx++) mx = fmaxf(mx, base[dy * 512 + dx]);
    }
    m[idx] = (mx > 0.f) ? 1.f : 0.f;
}

__global__ __launch_bounds__(256) void k_scan(
    const float* __restrict__ m, int* __restrict__ fgi, int* __restrict__ bgi,
    int* __restrict__ counts, float* __restrict__ kmc, int* __restrict__ p2s)
{
    const int b = blockIdx.x, t = threadIdx.x;
    const float* mb = m + (size_t)b * N;
    __shared__ int sfg[256], sbg[256];
    bool isf[16];
    int cf = 0, cb_ = 0;
    #pragma unroll
    for (int j = 0; j < 16; j++) {
        bool f = mb[t * 16 + j] != 0.f;
        isf[j] = f; cf += f ? 1 : 0; cb_ += f ? 0 : 1;
    }
    sfg[t] = cf; sbg[t] = cb_;
    __syncthreads();
    for (int off = 1; off < 256; off <<= 1) {
        int vf = (t >= off) ? sfg[t - off] : 0;
        int vb = (t >= off) ? sbg[t - off] : 0;
        __syncthreads();
        sfg[t] += vf; sbg[t] += vb;
        __syncthreads();
    }
    int basef = sfg[t] - cf, baseb = sbg[t] - cb_;
    int nfg = sfg[255], nbg = sbg[255];
    #pragma unroll
    for (int j = 0; j < 16; j++) {
        int p = t * 16 + j;
        if (isf[j]) { fgi[b * N + basef] = p; p2s[b * N + p] = basef | (1 << 30); basef++; }
        else        { bgi[b * N + baseb] = p; p2s[b * N + p] = baseb; baseb++; }
    }
    if (t == 0) {
        counts[b * 4 + 0] = nfg;
        counts[b * 4 + 1] = (nfg + 127) & ~127;
        counts[b * 4 + 2] = nbg;
        counts[b * 4 + 3] = (nbg + 127) & ~127;
    }
    for (int j = t; j < N; j += 256) kmc[b * N + j] = (j < nbg) ? 1.f : 0.f;
}

__global__ void k_padzero(const int* __restrict__ counts,
                          ushort* __restrict__ Qc, ushort* __restrict__ Kc)
{
    int b = blockIdx.x, t = threadIdx.x;
    int nfg = counts[b * 4], nfgp = counts[b * 4 + 1];
    int nbg = counts[b * 4 + 2], nbgp = counts[b * 4 + 3];
    for (int i = t; i < (nfgp - nfg) * CH; i += 256) Qc[((size_t)b * N + nfg) * CH + i] = 0;
    for (int i = t; i < (nbgp - nbg) * CH; i += 256) Kc[((size_t)b * N + nbg) * CH + i] = 0;
}

__global__ void k_zero(uint4* __restrict__ AFt4, uint4* __restrict__ vis4)
{
    int idx = blockIdx.x * 256 + threadIdx.x;
    uint4 z = {0, 0, 0, 0};
    if (idx < BATCH * N * CH * 2 / 16) AFt4[idx] = z;
    else                               vis4[idx - BATCH * N * CH * 2 / 16] = z;
}

// ---------------- weight/feature prep ----------------
__global__ void k_wconv(const float* __restrict__ Kw, const float* __restrict__ fw,
                        ushort* __restrict__ Kwb, ushort* __restrict__ fwb)
{
    int i = blockIdx.x * 256 + threadIdx.x;
    if (i < CH * CIN) Kwb[i] = f2bf(Kw[i]);
    else              fwb[i - CH * CIN] = f2bf(fw[i - CH * CIN]);
}

__global__ __launch_bounds__(256) void k_tr(const float* __restrict__ src,
                                            ushort* __restrict__ dst, int C)
{
    __shared__ float Ls[64][65];
    const int ci0 = blockIdx.x * 64, n0 = blockIdx.y * 64, b = blockIdx.z;
    const float* s = src + (size_t)b * C * 4096;
    const int t = threadIdx.x;
    #pragma unroll
    for (int it = 0; it < 4; it++) {
        int f4 = it * 256 + t;
        int r = f4 >> 4, c4 = f4 & 15;
        float4 v = *(const float4*)(s + (size_t)(ci0 + r) * 4096 + n0 + c4 * 4);
        Ls[r][c4 * 4 + 0] = v.x; Ls[r][c4 * 4 + 1] = v.y;
        Ls[r][c4 * 4 + 2] = v.z; Ls[r][c4 * 4 + 3] = v.w;
    }
    __syncthreads();
    ushort* d = dst + (size_t)b * 4096 * C;
    #pragma unroll
    for (int it = 0; it < 8; it++) {
        int p = it * 256 + t;
        int rn = p >> 5, cc2 = p & 31;
        uint val = (uint)f2bf(Ls[cc2 * 2][rn]) | ((uint)f2bf(Ls[cc2 * 2 + 1][rn]) << 16);
        *(uint*)(d + (size_t)(n0 + rn) * C + ci0 + cc2 * 2) = val;
    }
}

__global__ void k_vgather(const float* __restrict__ x, const int* __restrict__ bgi,
                          const int* __restrict__ counts, ushort* __restrict__ xc)
{
    int bc = blockIdx.x;
    int b = bc >> 8, c = bc & 255;
    int nbg = counts[b * 4 + 2], nbgp = counts[b * 4 + 3];
    const float* xr = x + ((size_t)b * CH + c) * N;
    const int* bi = bgi + (size_t)b * N;
    ushort* dst = xc + ((size_t)b * CH + c) * N;
    for (int j = threadIdx.x; j < nbgp; j += 256)
        dst[j] = (j < nbg) ? f2bf(xr[bi[j]]) : (ushort)0;
}

// ---------------- feats GEMM (dense) ----------------
__global__ __launch_bounds__(128) void k_feats(
    const ushort* __restrict__ Kwb, const ushort* __restrict__ xT,
    const ushort* __restrict__ dvtT, const float* __restrict__ Kb,
    float* __restrict__ FnT)
{
    __shared__ ushort SH[(64 + 128) * 64];
    const int b = blockIdx.z;
    const int n0 = blockIdx.x * 128, m0 = blockIdx.y * 64;
    const int lane = threadIdx.x & 63, wid = threadIdx.x >> 6;
    const int wn = (wid & 1) * 64;
    f32x4 acc[4][4]; zero_acc(acc);
    gemm_core<1, 2>(Kwb, CIN, m0,
                    xT + (size_t)b * N * CH, CH, CH,
                    dvtT + (size_t)b * N * DVC, DVC,
                    n0, CIN, SH, SH + 64 * 64, acc);
    float* Fb = FnT + (size_t)b * N * CH;
    #pragma unroll
    for (int i = 0; i < 4; i++) {
        int mbase = m0 + i * 16 + ((lane >> 4) * 4);
        float4 bias = *(const float4*)(Kb + mbase);
        #pragma unroll
        for (int j = 0; j < 4; j++) {
            int n = n0 + wn + j * 16 + (lane & 15);
            float4 o;
            o.x = acc[i][j][0] + bias.x; o.y = acc[i][j][1] + bias.y;
            o.z = acc[i][j][2] + bias.z; o.w = acc[i][j][3] + bias.w;
            *(float4*)(Fb + (size_t)n * CH + mbase) = o;
        }
    }
}

__global__ __launch_bounds__(256) void k_normalize(
    const float* __restrict__ FnT, const int* __restrict__ p2s,
    ushort* __restrict__ Qc, ushort* __restrict__ Kc)
{
    const int t = threadIdx.x, lane = t & 63, wid = t >> 6;
    const int g = blockIdx.x * 4 + wid;
    const int b = g >> 12;
    const float* src = FnT + (size_t)g * CH;
    float4 v = *(const float4*)(src + lane * 4);
    float s = v.x * v.x + v.y * v.y + v.z * v.z + v.w * v.w;
    #pragma unroll
    for (int mm = 1; mm < 64; mm <<= 1) s += __shfl_xor(s, mm);
    float inv_ = 1.f / (sqrtf(s) + 1e-8f);
    int sl = p2s[g];
    ushort* dst = (sl & (1 << 30)) ? Qc : Kc;
    int slot = sl & 0x3FFFFFFF;
    ushort4 o = { f2bf(v.x * inv_), f2bf(v.y * inv_), f2bf(v.z * inv_), f2bf(v.w * inv_) };
    *(ushort4*)(dst + ((size_t)b * N + slot) * CH + lane * 4) = o;
}

// ---------------- score GEMM (compact) ----------------
__global__ __launch_bounds__(256) void k_score(
    const ushort* __restrict__ Qc, const ushort* __restrict__ Kc,
    const float* __restrict__ kmc, const int* __restrict__ counts,
    ushort* __restrict__ P)
{
    const int b = blockIdx.z;
    const int nfgp = counts[b * 4 + 1], nbgp = counts[b * 4 + 3];
    const int m0 = blockIdx.y * 128, n0 = blockIdx.x * 128;
    if (m0 >= nfgp || n0 >= nbgp) return;
    __shared__ ushort SH[(128 + 128) * 64];
    const int t = threadIdx.x, lane = t & 63, wid = t >> 6;
    const int wm = (wid >> 1) * 64, wn = (wid & 1) * 64;
    const ushort* Qb = Qc + (size_t)b * N * CH;
    const ushort* Kb_ = Kc + (size_t)b * N * CH;
    f32x4 acc[4][4]; zero_acc(acc);
    gemm_core<2, 2>(Qb, CH, m0, Kb_, CH, CH, Kb_, CH, n0, CH, SH, SH + 128 * 64, acc);

    float km[4];
    #pragma unroll
    for (int j = 0; j < 4; j++) km[j] = kmc[(size_t)b * N + n0 + wn + j * 16 + (lane & 15)];

    ushort* Cs = SH;
    #pragma unroll
    for (int i = 0; i < 4; i++) {
        int rbase = wm + i * 16 + ((lane >> 4) * 4);
        #pragma unroll
        for (int j = 0; j < 4; j++) {
            int cl = wn + j * 16 + (lane & 15);
            #pragma unroll
            for (int r = 0; r < 4; r++) {
                float p = km[j] * __expf(20.f * acc[i][j][r] - 20.f);
                Cs[(rbase + r) * 128 + cl] = f2bf(p);
            }
        }
    }
    __syncthreads();
    ushort* Pb = P + (size_t)b * PBS;
    #pragma unroll
    for (int it = 0; it < 8; it++) {
        int v8 = it * 256 + t;
        int row = v8 >> 4, c8 = (v8 & 15) * 8;
        *(uint4*)(Pb + (size_t)(m0 + row) * nbgp + n0 + c8) = *(const uint4*)(Cs + row * 128 + c8);
    }
}

// rowsum -> inv[qi] (compact)
__global__ __launch_bounds__(256) void k_rowsum(
    const ushort* __restrict__ P, const int* __restrict__ counts,
    float* __restrict__ inv)
{
    const int t = threadIdx.x, lane = t & 63, wid = t >> 6;
    const int g = blockIdx.x * 4 + wid;
    const int b = g >> 12, qi = g & 4095;
    const int nfgp = counts[b * 4 + 1], nbgp = counts[b * 4 + 3];
    if (qi >= nfgp) return;
    const ushort* row = P + (size_t)b * PBS + (size_t)qi * nbgp;
    float s = 0.f;
    for (int it = 0; it < 8; it++) {
        int base = it * 512 + lane * 8;
        if (base < nbgp) {
            uint4 v = *(const uint4*)(row + base);
            const ushort* u = (const ushort*)&v;
            #pragma unroll
            for (int e = 0; e < 8; e++) s += bf2f(u[e]);
        }
    }
    #pragma unroll
    for (int mm = 1; mm < 64; mm <<= 1) s += __shfl_xor(s, mm);
    if (lane == 0) inv[g] = (s > 0.f) ? 1.f / s : 0.f;
}

// ---------------- PV GEMM (compact) ----------------
__global__ __launch_bounds__(128) void k_att_fore(
    const ushort* __restrict__ xc, const ushort* __restrict__ P,
    const float* __restrict__ inv, const int* __restrict__ fgi,
    const int* __restrict__ counts, ushort* __restrict__ AFt)
{
    const int b = blockIdx.z;
    const int nfg = counts[b * 4], nfgp = counts[b * 4 + 1], nbgp = counts[b * 4 + 3];
    const int n0 = blockIdx.x * 128;
    const int m0 = blockIdx.y * 64;
    if (n0 >= nfgp) return;
    __shared__ ushort SH[(64 + 128) * 64];
    const int lane = threadIdx.x & 63, wid = threadIdx.x >> 6;
    const int wn = (wid & 1) * 64;
    const ushort* Pb = P + (size_t)b * PBS;
    f32x4 acc[4][4]; zero_acc(acc);
    gemm_core<1, 2>(xc + (size_t)b * CH * N, N, m0,
                    Pb, nbgp, 1 << 30, Pb, nbgp,
                    n0, nbgp, SH, SH + 64 * 64, acc);
    const float* invb = inv + (size_t)b * N;
    const int* fb = fgi + (size_t)b * N;
    ushort* Ab = AFt + (size_t)b * N * CH;
    #pragma unroll
    for (int j = 0; j < 4; j++) {
        int qi = n0 + wn + j * 16 + (lane & 15);
        if (qi < nfg) {
            int q = fb[qi];
            float iq = invb[qi];
            #pragma unroll
            for (int i = 0; i < 4; i++) {
                int mbase = m0 + i * 16 + ((lane >> 4) * 4);
                ushort4 o = { f2bf(acc[i][j][0] * iq), f2bf(acc[i][j][1] * iq),
                              f2bf(acc[i][j][2] * iq), f2bf(acc[i][j][3] * iq) };
                *(ushort4*)(Ab + (size_t)q * CH + mbase) = o;
            }
        }
    }
}

// ---------------- fused GEMM + blend (dense) ----------------
__global__ __launch_bounds__(128) void k_fused(
    const ushort* __restrict__ fwb, const ushort* __restrict__ AFt,
    const ushort* __restrict__ xT, const float* __restrict__ x,
    const float* __restrict__ m_, float* __restrict__ out)
{
    __shared__ ushort SH[(64 + 128) * 64];
    const int b = blockIdx.z;
    const int n0 = blockIdx.x * 128, m0 = blockIdx.y * 64;
    const int lane = threadIdx.x & 63, wid = threadIdx.x >> 6;
    const int wn = (wid & 1) * 64;
    f32x4 acc[4][4]; zero_acc(acc);
    gemm_core<1, 2>(fwb, KC, m0,
                    AFt + (size_t)b * N * CH, CH, CH,
                    xT + (size_t)b * N * CH, CH,
                    n0, KC, SH, SH + 64 * 64, acc);
    const float* mb = m_ + (size_t)b * N;
    const float* xc_ = x + (size_t)b * CH * N;
    float* ob = out + (size_t)b * CH * N;
    #pragma unroll
    for (int j = 0; j < 4; j++) {
        int n = n0 + wn + j * 16 + (lane & 15);
        float mv = mb[n];
        #pragma unroll
        for (int i = 0; i < 4; i++) {
            int mbase = m0 + i * 16 + ((lane >> 4) * 4);
            #pragma unroll
            for (int r = 0; r < 4; r++) {
                int c = mbase + r;
                ob[(size_t)c * N + n] = (mv != 0.f) ? acc[i][j][r] : xc_[(size_t)c * N + n];
            }
        }
    }
}

// ---------------- colsum (coalesced, row-major sweep) ----------------
// part[qc][b*N+ki] = sum_{q in chunk qc} inv[q] * P[q][ki]
__global__ __launch_bounds__(256) void k_colsum(
    const ushort* __restrict__ P, const float* __restrict__ inv,
    const int* __restrict__ counts, float* __restrict__ part)
{
    const int b = blockIdx.z, qc = blockIdx.y, t = threadIdx.x;
    const int nfg = counts[b * 4], nbgp = counts[b * 4 + 3];
    const int ki0 = blockIdx.x * 2048 + t * 8;
    if (ki0 >= nbgp) return;
    const int qchunk = (nfg + QCH - 1) / QCH;
    const int q0 = qc * qchunk, q1 = min(q0 + qchunk, nfg);
    const ushort* base = P + (size_t)b * PBS + (size_t)q0 * nbgp + ki0;
    const float* ib = inv + (size_t)b * N;
    float acc[8] = {};
    int q = q0;
    for (; q + 4 <= q1; q += 4) {
        uint4 v0 = *(const uint4*)(base);
        uint4 v1 = *(const uint4*)(base + (size_t)nbgp);
        uint4 v2 = *(const uint4*)(base + 2 * (size_t)nbgp);
        uint4 v3 = *(const uint4*)(base + 3 * (size_t)nbgp);
        float i0 = ib[q], i1 = ib[q + 1], i2 = ib[q + 2], i3 = ib[q + 3];
        const ushort* u0 = (const ushort*)&v0;
        const ushort* u1 = (const ushort*)&v1;
        const ushort* u2 = (const ushort*)&v2;
        const ushort* u3 = (const ushort*)&v3;
        #pragma unroll
        for (int e = 0; e < 8; e++)
            acc[e] += bf2f(u0[e]) * i0 + bf2f(u1[e]) * i1 + bf2f(u2[e]) * i2 + bf2f(u3[e]) * i3;
        base += 4 * (size_t)nbgp;
    }
    for (; q < q1; q++) {
        uint4 v = *(const uint4*)(base);
        float iq = ib[q];
        const ushort* u = (const ushort*)&v;
        #pragma unroll
        for (int e = 0; e < 8; e++) acc[e] += bf2f(u[e]) * iq;
        base += (size_t)nbgp;
    }
    float* pp = part + (size_t)qc * (BATCH * N) + (size_t)b * N + ki0;
    float4 o0 = {acc[0], acc[1], acc[2], acc[3]};
    float4 o1 = {acc[4], acc[5], acc[6], acc[7]};
    *(float4*)(pp)     = o0;
    *(float4*)(pp + 4) = o1;
}

__global__ void k_colsum_final(const float* __restrict__ part, const int* __restrict__ bgi,
                               const int* __restrict__ counts, float* __restrict__ vis)
{
    int g = blockIdx.x * 256 + threadIdx.x;
    int b = g >> 12, ki = g & 4095;
    if (ki >= counts[b * 4 + 2]) return;
    float s = 0.f;
    #pragma unroll
    for (int j = 0; j < QCH; j++) s += part[(size_t)j * (BATCH * N) + g];
    vis[(size_t)b * N + bgi[(size_t)b * N + ki]] = s;
}

__global__ void k_vismax(const float* __restrict__ vis, float* __restrict__ maxv)
{
    __shared__ float red[256];
    int t = threadIdx.x;
    float mx = 0.f;
    for (int i = t; i < BATCH * N; i += 256) mx = fmaxf(mx, vis[i]);
    red[t] = mx; __syncthreads();
    for (int s = 128; s > 0; s >>= 1) { if (t < s) red[t] = fmaxf(red[t], red[t + s]); __syncthreads(); }
    if (t == 0) maxv[0] = red[0];
}

__global__ void k_attmask(const float* __restrict__ vis, const float* __restrict__ maxv,
                          float* __restrict__ amask)
{
    int idx = blockIdx.x * 256 + threadIdx.x;
    int b = idx >> 18;
    int r = idx & 262143;
    int Y = r >> 9, X = r & 511;
    amask[idx] = vis[(size_t)b * N + (Y >> 3) * 64 + (X >> 3)] / maxv[0];
}

// ---------------- launch ----------------
extern "C" void kernel_launch(void* const* d_in, const int* in_sizes, int n_in,
                              void* d_out, int out_size, void* d_ws, size_t ws_size,
                              hipStream_t stream)
{
    const float* x    = (const float*)d_in[0];
    const float* mask = (const float*)d_in[1];
    const float* dvt  = (const float*)d_in[2];
    const float* Kw   = (const float*)d_in[3];
    const float* Kb   = (const float*)d_in[4];
    const float* fw   = (const float*)d_in[5];
    float* out = (float*)d_out;

    char* ws = (char*)d_ws;
    float*  m    = (float*)(ws + OFF_M);
    float*  inv  = (float*)(ws + OFF_INV);
    float*  vis  = (float*)(ws + OFF_VIS);
    float*  maxv = (float*)(ws + OFF_MAXV);
    int*    cnt  = (int*)  (ws + OFF_CNT);
    int*    fgi  = (int*)  (ws + OFF_FGI);
    int*    bgi  = (int*)  (ws + OFF_BGI);
    int*    p2s  = (int*)  (ws + OFF_P2S);
    float*  kmc  = (float*)(ws + OFF_KMC);
    float*  part = (float*)(ws + OFF_PART);
    ushort* Kwb  = (ushort*)(ws + OFF_KWB);
    ushort* fwb  = (ushort*)(ws + OFF_FWB);
    ushort* xT   = (ushort*)(ws + OFF_XT);
    ushort* dvtT = (ushort*)(ws + OFF_DVTT);
    ushort* Qc   = (ushort*)(ws + OFF_QC);
    ushort* Kcc  = (ushort*)(ws + OFF_KCC);
    ushort* xc   = (ushort*)(ws + OFF_XC);
    ushort* AFt  = (ushort*)(ws + OFF_AFT);
    ushort* P    = (ushort*)(ws + OFF_P);
    float*  FnT  = (float*)(ws + OFF_FNT);

    k_maskpool   <<<dim3(BATCH * N / 256), 256, 0, stream>>>(mask, m);
    k_scan       <<<dim3(BATCH), 256, 0, stream>>>(m, fgi, bgi, cnt, kmc, p2s);
    k_wconv      <<<dim3((CH * CIN + CH * KC) / 256), 256, 0, stream>>>(Kw, fw, Kwb, fwb);
    k_tr         <<<dim3(CH / 64, 64, BATCH), 256, 0, stream>>>(x, xT, CH);
    k_tr         <<<dim3(DVC / 64, 64, BATCH), 256, 0, stream>>>(dvt, dvtT, DVC);
    k_feats      <<<dim3(N / 128, CH / 64, BATCH), 128, 0, stream>>>(Kwb, xT, dvtT, Kb, FnT);
    k_padzero    <<<dim3(BATCH), 256, 0, stream>>>(cnt, Qc, Kcc);
    k_zero       <<<dim3((BATCH * N * CH * 2 / 16 + BATCH * N * 4 / 16) / 256), 256, 0, stream>>>(
                     (uint4*)AFt, (uint4*)vis);
    k_normalize  <<<dim3(BATCH * N / 4), 256, 0, stream>>>(FnT, p2s, Qc, Kcc);
    k_vgather    <<<dim3(BATCH * CH), 256, 0, stream>>>(x, bgi, cnt, xc);
    k_score      <<<dim3(N / 128, N / 128, BATCH), 256, 0, stream>>>(Qc, Kcc, kmc, cnt, P);
    k_rowsum     <<<dim3(BATCH * N / 4), 256, 0, stream>>>(P, cnt, inv);
    k_att_fore   <<<dim3(N / 128, CH / 64, BATCH), 128, 0, stream>>>(xc, P, inv, fgi, cnt, AFt);
    k_colsum     <<<dim3(2, QCH, BATCH), 256, 0, stream>>>(P, inv, cnt, part);
    k_colsum_final<<<dim3(BATCH * N / 256), 256, 0, stream>>>(part, bgi, cnt, vis);
    k_vismax     <<<dim3(1), 256, 0, stream>>>(vis, maxv);
    k_fused      <<<dim3(N / 128, CH / 64, BATCH), 128, 0, stream>>>(fwb, AFt, xT, x, m, out);
    k_attmask    <<<dim3(BATCH * 512 * 512 / 256), 256, 0, stream>>>(vis, maxv, out + (size_t)BATCH * CH * N);
}

// Round 5
// 214.061 us; speedup vs baseline: 1.5632x; 1.0149x over previous
//
#include <hip/hip_runtime.h>
#include <hip/hip_bf16.h>

typedef __attribute__((ext_vector_type(8))) short short8;
typedef __attribute__((ext_vector_type(4))) float f32x4;
typedef unsigned int uint;
typedef unsigned short ushort;

constexpr int BATCH = 4;
constexpr int CH    = 256;
constexpr int N     = 4096;   // 64*64
constexpr int DVC   = 768;
constexpr int CIN   = 1024;   // CH + DVC
constexpr int KC    = 512;    // 2*CH
constexpr int PBS   = 5 * 1024 * 1024;  // P per-batch stride (elements)
constexpr int QCH   = 32;     // colsum q-chunks
constexpr int SPLITK = 4;     // att_fore K-split

// ---------------- workspace layout (bytes), total 148 MB ----------------
constexpr size_t OFF_M    = 0;                       // 16384 f32
constexpr size_t OFF_INV  = 64ull << 10;             // 16384 f32 (compact, per fg slot)
constexpr size_t OFF_VIS  = 128ull << 10;            // 16384 f32
constexpr size_t OFF_MAXV = 192ull << 10;            // 1 f32
constexpr size_t OFF_CNT  = 196ull << 10;            // 16 ints {nfg,nfgp,nbg,nbgp} x4
constexpr size_t OFF_FGI  = 256ull << 10;            // 16384 int
constexpr size_t OFF_BGI  = 320ull << 10;            // 16384 int
constexpr size_t OFF_P2S  = 384ull << 10;            // 16384 int
constexpr size_t OFF_KMC  = 448ull << 10;            // 16384 f32
constexpr size_t OFF_PART = 512ull << 10;            // QCH*16384 f32 = 2MB
constexpr size_t OFF_KWB  = 3ull << 20;              // 512KB bf16
constexpr size_t OFF_FWB  = OFF_KWB + (512ull << 10);// 256KB bf16
constexpr size_t OFF_XT   = 4ull << 20;              // [b][n][256] bf16 = 8MB
constexpr size_t OFF_DVTT = 12ull << 20;             // [b][n][768] bf16 = 24MB (dead after feats)
constexpr size_t OFF_QC   = OFF_DVTT;                //   [b][qi][256] bf16 = 8MB
constexpr size_t OFF_KCC  = OFF_DVTT + (8ull << 20); //   [b][ki][256] bf16 = 8MB
constexpr size_t OFF_XC   = OFF_DVTT + (16ull << 20);//   [b][c][4096] bf16 = 8MB
constexpr size_t OFF_AFT  = 36ull << 20;             // [b][n][256] bf16 = 8MB (scatter, bg rows unused)
constexpr size_t OFF_P    = 44ull << 20;             // compact P bf16, 4 x PBS = 40MB
constexpr size_t OFF_FNT  = OFF_P;                   // [b][n][256] f32 = 16MB overlay (dead pre-score)
constexpr size_t OFF_AFP  = 84ull << 20;             // f32 partials [sk][b][qi][c] = 64MB

// ---------------- helpers ----------------
__device__ __forceinline__ ushort f2bf(float f) {
    __hip_bfloat16 h = __float2bfloat16(f);
    return __builtin_bit_cast(ushort, h);
}
__device__ __forceinline__ float bf2f(ushort u) {
    uint v = (uint)u << 16;
    return __builtin_bit_cast(float, v);
}

typedef const __attribute__((address_space(1))) uint* gptr_t;
typedef __attribute__((address_space(3))) uint* lptr_t;
__device__ __forceinline__ void gload_lds16(const void* g, void* l) {
    __builtin_amdgcn_global_load_lds((gptr_t)g, (lptr_t)l, 16, 0, 0);
}

// ---------------- shared GEMM mainloop ----------------
template<int WM, int WN>
__device__ __forceinline__ void gemm_core(
    const ushort* __restrict__ A0, int lda, int m0,
    const ushort* __restrict__ B0, int ldb0, int kend0,
    const ushort* __restrict__ B1, int ldb1,
    int n0, int K,
    ushort* AsL, ushort* BsL, f32x4 acc[4][4])
{
    constexpr int NW = WM * WN, BM = WM * 64, BN = WN * 64;
    const int t = threadIdx.x, lane = t & 63, wid = t >> 6;
    const int wm = (wid / WN) * 64, wn = (wid % WN) * 64;

    for (int k0 = 0; k0 < K; k0 += 64) {
        #pragma unroll
        for (int c = wid; c < BM / 8; c += NW) {
            const ushort* g = A0 + (size_t)(m0 + c * 8 + (lane >> 3)) * lda + (k0 + (lane & 7) * 8);
            gload_lds16(g, AsL + c * 512);
        }
        const ushort* Bsrc = (k0 < kend0) ? B0 : B1;
        const int ldb = (k0 < kend0) ? ldb0 : ldb1;
        const int kc  = (k0 < kend0) ? k0 : (k0 - kend0);
        #pragma unroll
        for (int c = wid; c < BN / 8; c += NW) {
            const ushort* g = Bsrc + (size_t)(n0 + c * 8 + (lane >> 3)) * ldb + (kc + (lane & 7) * 8);
            gload_lds16(g, BsL + c * 512);
        }
        __syncthreads();

        const int ra = wm + (lane & 15), rb = wn + (lane & 15), ko = (lane >> 4) * 8;
        #pragma unroll
        for (int kk = 0; kk < 64; kk += 32) {
            short8 a[4], b[4];
            #pragma unroll
            for (int i = 0; i < 4; i++) a[i] = *(const short8*)(AsL + (ra + i * 16) * 64 + kk + ko);
            #pragma unroll
            for (int j = 0; j < 4; j++) b[j] = *(const short8*)(BsL + (rb + j * 16) * 64 + kk + ko);
            #pragma unroll
            for (int i = 0; i < 4; i++)
                #pragma unroll
                for (int j = 0; j < 4; j++)
                    acc[i][j] = __builtin_amdgcn_mfma_f32_16x16x32_bf16(a[i], b[j], acc[i][j], 0, 0, 0);
        }
        __syncthreads();
    }
}

__device__ __forceinline__ void zero_acc(f32x4 acc[4][4]) {
    f32x4 z = {0.f, 0.f, 0.f, 0.f};
    #pragma unroll
    for (int i = 0; i < 4; i++)
        #pragma unroll
        for (int j = 0; j < 4; j++) acc[i][j] = z;
}

// ---------------- mask + compaction ----------------
__global__ void k_maskpool(const float* __restrict__ mask, float* __restrict__ m)
{
    int idx = blockIdx.x * 256 + threadIdx.x;
    int b = idx >> 12, p = idx & 4095;
    int y = p >> 6, x = p & 63;
    const float* base = mask + (size_t)b * 512 * 512 + (y * 8) * 512 + x * 8;
    float mx = 0.f;
    for (int dy = 0; dy < 8; dy++) {
        #pragma unroll
        for (int dx = 0; dx < 8; dx++) mx = fmaxf(mx, base[dy * 512 + dx]);
    }
    m[idx] = (mx > 0.f) ? 1.f : 0.f;
}

__global__ __launch_bounds__(256) void k_scan(
    const float* __restrict__ m, int* __restrict__ fgi, int* __restrict__ bgi,
    int* __restrict__ counts, float* __restrict__ kmc, int* __restrict__ p2s)
{
    const int b = blockIdx.x, t = threadIdx.x;
    const float* mb = m + (size_t)b * N;
    __shared__ int sfg[256], sbg[256];
    bool isf[16];
    int cf = 0, cb_ = 0;
    #pragma unroll
    for (int j = 0; j < 16; j++) {
        bool f = mb[t * 16 + j] != 0.f;
        isf[j] = f; cf += f ? 1 : 0; cb_ += f ? 0 : 1;
    }
    sfg[t] = cf; sbg[t] = cb_;
    __syncthreads();
    for (int off = 1; off < 256; off <<= 1) {
        int vf = (t >= off) ? sfg[t - off] : 0;
        int vb = (t >= off) ? sbg[t - off] : 0;
        __syncthreads();
        sfg[t] += vf; sbg[t] += vb;
        __syncthreads();
    }
    int basef = sfg[t] - cf, baseb = sbg[t] - cb_;
    int nfg = sfg[255], nbg = sbg[255];
    #pragma unroll
    for (int j = 0; j < 16; j++) {
        int p = t * 16 + j;
        if (isf[j]) { fgi[b * N + basef] = p; p2s[b * N + p] = basef | (1 << 30); basef++; }
        else        { bgi[b * N + baseb] = p; p2s[b * N + p] = baseb; baseb++; }
    }
    if (t == 0) {
        counts[b * 4 + 0] = nfg;
        counts[b * 4 + 1] = (nfg + 127) & ~127;
        counts[b * 4 + 2] = nbg;
        counts[b * 4 + 3] = (nbg + 127) & ~127;
    }
    for (int j = t; j < N; j += 256) kmc[b * N + j] = (j < nbg) ? 1.f : 0.f;
}

__global__ void k_padzero(const int* __restrict__ counts,
                          ushort* __restrict__ Qc, ushort* __restrict__ Kc)
{
    int b = blockIdx.x, t = threadIdx.x;
    int nfg = counts[b * 4], nfgp = counts[b * 4 + 1];
    int nbg = counts[b * 4 + 2], nbgp = counts[b * 4 + 3];
    for (int i = t; i < (nfgp - nfg) * CH; i += 256) Qc[((size_t)b * N + nfg) * CH + i] = 0;
    for (int i = t; i < (nbgp - nbg) * CH; i += 256) Kc[((size_t)b * N + nbg) * CH + i] = 0;
}

// zero vis only (64KB)
__global__ void k_zero(uint4* __restrict__ vis4)
{
    int idx = blockIdx.x * 256 + threadIdx.x;
    uint4 z = {0, 0, 0, 0};
    vis4[idx] = z;
}

// ---------------- weight/feature prep ----------------
__global__ void k_wconv(const float* __restrict__ Kw, const float* __restrict__ fw,
                        ushort* __restrict__ Kwb, ushort* __restrict__ fwb)
{
    int i = blockIdx.x * 256 + threadIdx.x;
    if (i < CH * CIN) Kwb[i] = f2bf(Kw[i]);
    else              fwb[i - CH * CIN] = f2bf(fw[i - CH * CIN]);
}

__global__ __launch_bounds__(256) void k_tr(const float* __restrict__ src,
                                            ushort* __restrict__ dst, int C)
{
    __shared__ float Ls[64][65];
    const int ci0 = blockIdx.x * 64, n0 = blockIdx.y * 64, b = blockIdx.z;
    const float* s = src + (size_t)b * C * 4096;
    const int t = threadIdx.x;
    #pragma unroll
    for (int it = 0; it < 4; it++) {
        int f4 = it * 256 + t;
        int r = f4 >> 4, c4 = f4 & 15;
        float4 v = *(const float4*)(s + (size_t)(ci0 + r) * 4096 + n0 + c4 * 4);
        Ls[r][c4 * 4 + 0] = v.x; Ls[r][c4 * 4 + 1] = v.y;
        Ls[r][c4 * 4 + 2] = v.z; Ls[r][c4 * 4 + 3] = v.w;
    }
    __syncthreads();
    ushort* d = dst + (size_t)b * 4096 * C;
    #pragma unroll
    for (int it = 0; it < 8; it++) {
        int p = it * 256 + t;
        int rn = p >> 5, cc2 = p & 31;
        uint val = (uint)f2bf(Ls[cc2 * 2][rn]) | ((uint)f2bf(Ls[cc2 * 2 + 1][rn]) << 16);
        *(uint*)(d + (size_t)(n0 + rn) * C + ci0 + cc2 * 2) = val;
    }
}

__global__ void k_vgather(const float* __restrict__ x, const int* __restrict__ bgi,
                          const int* __restrict__ counts, ushort* __restrict__ xc)
{
    int bc = blockIdx.x;
    int b = bc >> 8, c = bc & 255;
    int nbg = counts[b * 4 + 2], nbgp = counts[b * 4 + 3];
    const float* xr = x + ((size_t)b * CH + c) * N;
    const int* bi = bgi + (size_t)b * N;
    ushort* dst = xc + ((size_t)b * CH + c) * N;
    for (int j = threadIdx.x; j < nbgp; j += 256)
        dst[j] = (j < nbg) ? f2bf(xr[bi[j]]) : (ushort)0;
}

// ---------------- feats GEMM (dense) ----------------
__global__ __launch_bounds__(128) void k_feats(
    const ushort* __restrict__ Kwb, const ushort* __restrict__ xT,
    const ushort* __restrict__ dvtT, const float* __restrict__ Kb,
    float* __restrict__ FnT)
{
    __shared__ ushort SH[(64 + 128) * 64];
    const int b = blockIdx.z;
    const int n0 = blockIdx.x * 128, m0 = blockIdx.y * 64;
    const int lane = threadIdx.x & 63, wid = threadIdx.x >> 6;
    const int wn = (wid & 1) * 64;
    f32x4 acc[4][4]; zero_acc(acc);
    gemm_core<1, 2>(Kwb, CIN, m0,
                    xT + (size_t)b * N * CH, CH, CH,
                    dvtT + (size_t)b * N * DVC, DVC,
                    n0, CIN, SH, SH + 64 * 64, acc);
    float* Fb = FnT + (size_t)b * N * CH;
    #pragma unroll
    for (int i = 0; i < 4; i++) {
        int mbase = m0 + i * 16 + ((lane >> 4) * 4);
        float4 bias = *(const float4*)(Kb + mbase);
        #pragma unroll
        for (int j = 0; j < 4; j++) {
            int n = n0 + wn + j * 16 + (lane & 15);
            float4 o;
            o.x = acc[i][j][0] + bias.x; o.y = acc[i][j][1] + bias.y;
            o.z = acc[i][j][2] + bias.z; o.w = acc[i][j][3] + bias.w;
            *(float4*)(Fb + (size_t)n * CH + mbase) = o;
        }
    }
}

__global__ __launch_bounds__(256) void k_normalize(
    const float* __restrict__ FnT, const int* __restrict__ p2s,
    ushort* __restrict__ Qc, ushort* __restrict__ Kc)
{
    const int t = threadIdx.x, lane = t & 63, wid = t >> 6;
    const int g = blockIdx.x * 4 + wid;
    const int b = g >> 12;
    const float* src = FnT + (size_t)g * CH;
    float4 v = *(const float4*)(src + lane * 4);
    float s = v.x * v.x + v.y * v.y + v.z * v.z + v.w * v.w;
    #pragma unroll
    for (int mm = 1; mm < 64; mm <<= 1) s += __shfl_xor(s, mm);
    float inv_ = 1.f / (sqrtf(s) + 1e-8f);
    int sl = p2s[g];
    ushort* dst = (sl & (1 << 30)) ? Qc : Kc;
    int slot = sl & 0x3FFFFFFF;
    ushort4 o = { f2bf(v.x * inv_), f2bf(v.y * inv_), f2bf(v.z * inv_), f2bf(v.w * inv_) };
    *(ushort4*)(dst + ((size_t)b * N + slot) * CH + lane * 4) = o;
}

// ---------------- score GEMM (compact) ----------------
__global__ __launch_bounds__(256) void k_score(
    const ushort* __restrict__ Qc, const ushort* __restrict__ Kc,
    const float* __restrict__ kmc, const int* __restrict__ counts,
    ushort* __restrict__ P)
{
    const int b = blockIdx.z;
    const int nfgp = counts[b * 4 + 1], nbgp = counts[b * 4 + 3];
    const int m0 = blockIdx.y * 128, n0 = blockIdx.x * 128;
    if (m0 >= nfgp || n0 >= nbgp) return;
    __shared__ ushort SH[(128 + 128) * 64];
    const int t = threadIdx.x, lane = t & 63, wid = t >> 6;
    const int wm = (wid >> 1) * 64, wn = (wid & 1) * 64;
    const ushort* Qb = Qc + (size_t)b * N * CH;
    const ushort* Kb_ = Kc + (size_t)b * N * CH;
    f32x4 acc[4][4]; zero_acc(acc);
    gemm_core<2, 2>(Qb, CH, m0, Kb_, CH, CH, Kb_, CH, n0, CH, SH, SH + 128 * 64, acc);

    float km[4];
    #pragma unroll
    for (int j = 0; j < 4; j++) km[j] = kmc[(size_t)b * N + n0 + wn + j * 16 + (lane & 15)];

    ushort* Cs = SH;
    #pragma unroll
    for (int i = 0; i < 4; i++) {
        int rbase = wm + i * 16 + ((lane >> 4) * 4);
        #pragma unroll
        for (int j = 0; j < 4; j++) {
            int cl = wn + j * 16 + (lane & 15);
            #pragma unroll
            for (int r = 0; r < 4; r++) {
                float p = km[j] * __expf(20.f * acc[i][j][r] - 20.f);
                Cs[(rbase + r) * 128 + cl] = f2bf(p);
            }
        }
    }
    __syncthreads();
    ushort* Pb = P + (size_t)b * PBS;
    #pragma unroll
    for (int it = 0; it < 8; it++) {
        int v8 = it * 256 + t;
        int row = v8 >> 4, c8 = (v8 & 15) * 8;
        *(uint4*)(Pb + (size_t)(m0 + row) * nbgp + n0 + c8) = *(const uint4*)(Cs + row * 128 + c8);
    }
}

// rowsum -> inv[qi] (compact)
__global__ __launch_bounds__(256) void k_rowsum(
    const ushort* __restrict__ P, const int* __restrict__ counts,
    float* __restrict__ inv)
{
    const int t = threadIdx.x, lane = t & 63, wid = t >> 6;
    const int g = blockIdx.x * 4 + wid;
    const int b = g >> 12, qi = g & 4095;
    const int nfgp = counts[b * 4 + 1], nbgp = counts[b * 4 + 3];
    if (qi >= nfgp) return;
    const ushort* row = P + (size_t)b * PBS + (size_t)qi * nbgp;
    float s = 0.f;
    for (int it = 0; it < 8; it++) {
        int base = it * 512 + lane * 8;
        if (base < nbgp) {
            uint4 v = *(const uint4*)(row + base);
            const ushort* u = (const ushort*)&v;
            #pragma unroll
            for (int e = 0; e < 8; e++) s += bf2f(u[e]);
        }
    }
    #pragma unroll
    for (int mm = 1; mm < 64; mm <<= 1) s += __shfl_xor(s, mm);
    if (lane == 0) inv[g] = (s > 0.f) ? 1.f / s : 0.f;
}

// ---------------- PV GEMM (compact, split-K partials) ----------------
// AFp[sk][b][qi][c] = sum_{ki in chunk sk} xc[c][ki] * P[qi][ki]
__global__ __launch_bounds__(128) void k_att_fore(
    const ushort* __restrict__ xc, const ushort* __restrict__ P,
    const int* __restrict__ counts, float* __restrict__ AFp)
{
    const int b = blockIdx.z & (BATCH - 1);
    const int sk = blockIdx.z / BATCH;
    const int nfgp = counts[b * 4 + 1], nbgp = counts[b * 4 + 3];
    const int n0 = blockIdx.x * 128;   // qi tile
    const int m0 = blockIdx.y * 64;    // c tile
    if (n0 >= nfgp) return;
    const int kchunk = ((nbgp / 64 + SPLITK - 1) / SPLITK) * 64;
    const int k0s = sk * kchunk;
    const int len = min(kchunk, nbgp - k0s);

    const int lane = threadIdx.x & 63, wid = threadIdx.x >> 6;
    const int wn = (wid & 1) * 64;
    f32x4 acc[4][4]; zero_acc(acc);
    if (len > 0) {
        __shared__ ushort SH[(64 + 128) * 64];
        const ushort* Pb = P + (size_t)b * PBS + k0s;
        gemm_core<1, 2>(xc + (size_t)b * CH * N + k0s, N, m0,
                        Pb, nbgp, 1 << 30, Pb, nbgp,
                        n0, len, SH, SH + 64 * 64, acc);
    }
    float* Ap = AFp + ((size_t)(sk * BATCH + b) * N) * CH;
    #pragma unroll
    for (int j = 0; j < 4; j++) {
        int qi = n0 + wn + j * 16 + (lane & 15);
        #pragma unroll
        for (int i = 0; i < 4; i++) {
            int mbase = m0 + i * 16 + ((lane >> 4) * 4);
            float4 o = { acc[i][j][0], acc[i][j][1], acc[i][j][2], acc[i][j][3] };
            *(float4*)(Ap + (size_t)qi * CH + mbase) = o;
        }
    }
}

// reduce partials, scale by inv, scatter to dense AFt (bf16)
__global__ __launch_bounds__(256) void k_afreduce(
    const float* __restrict__ AFp, const float* __restrict__ inv,
    const int* __restrict__ fgi, const int* __restrict__ counts,
    ushort* __restrict__ AFt)
{
    const int t = threadIdx.x, lane = t & 63, wid = t >> 6;
    const int g = blockIdx.x * 4 + wid;       // b*N + qi
    const int b = g >> 12, qi = g & 4095;
    if (qi >= counts[b * 4]) return;          // nfg
    const size_t rowoff = ((size_t)b * N + qi) * CH + lane * 4;
    float4 s = *(const float4*)(AFp + rowoff);
    #pragma unroll
    for (int sk = 1; sk < SPLITK; sk++) {
        float4 v = *(const float4*)(AFp + (size_t)sk * BATCH * N * CH + rowoff);
        s.x += v.x; s.y += v.y; s.z += v.z; s.w += v.w;
    }
    float iq = inv[g];
    int q = fgi[g];
    ushort4 o = { f2bf(s.x * iq), f2bf(s.y * iq), f2bf(s.z * iq), f2bf(s.w * iq) };
    *(ushort4*)(AFt + ((size_t)b * N + q) * CH + lane * 4) = o;
}

// ---------------- fused GEMM + blend (dense) ----------------
__global__ __launch_bounds__(128) void k_fused(
    const ushort* __restrict__ fwb, const ushort* __restrict__ AFt,
    const ushort* __restrict__ xT, const float* __restrict__ x,
    const float* __restrict__ m_, float* __restrict__ out)
{
    __shared__ ushort SH[(64 + 128) * 64];
    const int b = blockIdx.z;
    const int n0 = blockIdx.x * 128, m0 = blockIdx.y * 64;
    const int lane = threadIdx.x & 63, wid = threadIdx.x >> 6;
    const int wn = (wid & 1) * 64;
    f32x4 acc[4][4]; zero_acc(acc);
    gemm_core<1, 2>(fwb, KC, m0,
                    AFt + (size_t)b * N * CH, CH, CH,
                    xT + (size_t)b * N * CH, CH,
                    n0, KC, SH, SH + 64 * 64, acc);
    const float* mb = m_ + (size_t)b * N;
    const float* xc_ = x + (size_t)b * CH * N;
    float* ob = out + (size_t)b * CH * N;
    #pragma unroll
    for (int j = 0; j < 4; j++) {
        int n = n0 + wn + j * 16 + (lane & 15);
        float mv = mb[n];
        #pragma unroll
        for (int i = 0; i < 4; i++) {
            int mbase = m0 + i * 16 + ((lane >> 4) * 4);
            #pragma unroll
            for (int r = 0; r < 4; r++) {
                int c = mbase + r;
                ob[(size_t)c * N + n] = (mv != 0.f) ? acc[i][j][r] : xc_[(size_t)c * N + n];
            }
        }
    }
}

// ---------------- colsum (coalesced, row-major sweep) ----------------
__global__ __launch_bounds__(256) void k_colsum(
    const ushort* __restrict__ P, const float* __restrict__ inv,
    const int* __restrict__ counts, float* __restrict__ part)
{
    const int b = blockIdx.z, qc = blockIdx.y, t = threadIdx.x;
    const int nfg = counts[b * 4], nbgp = counts[b * 4 + 3];
    const int ki0 = blockIdx.x * 2048 + t * 8;
    if (ki0 >= nbgp) return;
    const int qchunk = (nfg + QCH - 1) / QCH;
    const int q0 = qc * qchunk, q1 = min(q0 + qchunk, nfg);
    const ushort* base = P + (size_t)b * PBS + (size_t)q0 * nbgp + ki0;
    const float* ib = inv + (size_t)b * N;
    float acc[8] = {};
    int q = q0;
    for (; q + 4 <= q1; q += 4) {
        uint4 v0 = *(const uint4*)(base);
        uint4 v1 = *(const uint4*)(base + (size_t)nbgp);
        uint4 v2 = *(const uint4*)(base + 2 * (size_t)nbgp);
        uint4 v3 = *(const uint4*)(base + 3 * (size_t)nbgp);
        float i0 = ib[q], i1 = ib[q + 1], i2 = ib[q + 2], i3 = ib[q + 3];
        const ushort* u0 = (const ushort*)&v0;
        const ushort* u1 = (const ushort*)&v1;
        const ushort* u2 = (const ushort*)&v2;
        const ushort* u3 = (const ushort*)&v3;
        #pragma unroll
        for (int e = 0; e < 8; e++)
            acc[e] += bf2f(u0[e]) * i0 + bf2f(u1[e]) * i1 + bf2f(u2[e]) * i2 + bf2f(u3[e]) * i3;
        base += 4 * (size_t)nbgp;
    }
    for (; q < q1; q++) {
        uint4 v = *(const uint4*)(base);
        float iq = ib[q];
        const ushort* u = (const ushort*)&v;
        #pragma unroll
        for (int e = 0; e < 8; e++) acc[e] += bf2f(u[e]) * iq;
        base += (size_t)nbgp;
    }
    float* pp = part + (size_t)qc * (BATCH * N) + (size_t)b * N + ki0;
    float4 o0 = {acc[0], acc[1], acc[2], acc[3]};
    float4 o1 = {acc[4], acc[5], acc[6], acc[7]};
    *(float4*)(pp)     = o0;
    *(float4*)(pp + 4) = o1;
}

__global__ void k_colsum_final(const float* __restrict__ part, const int* __restrict__ bgi,
                               const int* __restrict__ counts, float* __restrict__ vis)
{
    int g = blockIdx.x * 256 + threadIdx.x;
    int b = g >> 12, ki = g & 4095;
    if (ki >= counts[b * 4 + 2]) return;
    float s = 0.f;
    #pragma unroll
    for (int j = 0; j < QCH; j++) s += part[(size_t)j * (BATCH * N) + g];
    vis[(size_t)b * N + bgi[(size_t)b * N + ki]] = s;
}

__global__ void k_vismax(const float* __restrict__ vis, float* __restrict__ maxv)
{
    __shared__ float red[256];
    int t = threadIdx.x;
    float mx = 0.f;
    for (int i = t; i < BATCH * N; i += 256) mx = fmaxf(mx, vis[i]);
    red[t] = mx; __syncthreads();
    for (int s = 128; s > 0; s >>= 1) { if (t < s) red[t] = fmaxf(red[t], red[t + s]); __syncthreads(); }
    if (t == 0) maxv[0] = red[0];
}

__global__ void k_attmask(const float* __restrict__ vis, const float* __restrict__ maxv,
                          float* __restrict__ amask)
{
    int idx = blockIdx.x * 256 + threadIdx.x;
    int b = idx >> 18;
    int r = idx & 262143;
    int Y = r >> 9, X = r & 511;
    amask[idx] = vis[(size_t)b * N + (Y >> 3) * 64 + (X >> 3)] / maxv[0];
}

// ---------------- launch ----------------
extern "C" void kernel_launch(void* const* d_in, const int* in_sizes, int n_in,
                              void* d_out, int out_size, void* d_ws, size_t ws_size,
                              hipStream_t stream)
{
    const float* x    = (const float*)d_in[0];
    const float* mask = (const float*)d_in[1];
    const float* dvt  = (const float*)d_in[2];
    const float* Kw   = (const float*)d_in[3];
    const float* Kb   = (const float*)d_in[4];
    const float* fw   = (const float*)d_in[5];
    float* out = (float*)d_out;

    char* ws = (char*)d_ws;
    float*  m    = (float*)(ws + OFF_M);
    float*  inv  = (float*)(ws + OFF_INV);
    float*  vis  = (float*)(ws + OFF_VIS);
    float*  maxv = (float*)(ws + OFF_MAXV);
    int*    cnt  = (int*)  (ws + OFF_CNT);
    int*    fgi  = (int*)  (ws + OFF_FGI);
    int*    bgi  = (int*)  (ws + OFF_BGI);
    int*    p2s  = (int*)  (ws + OFF_P2S);
    float*  kmc  = (float*)(ws + OFF_KMC);
    float*  part = (float*)(ws + OFF_PART);
    ushort* Kwb  = (ushort*)(ws + OFF_KWB);
    ushort* fwb  = (ushort*)(ws + OFF_FWB);
    ushort* xT   = (ushort*)(ws + OFF_XT);
    ushort* dvtT = (ushort*)(ws + OFF_DVTT);
    ushort* Qc   = (ushort*)(ws + OFF_QC);
    ushort* Kcc  = (ushort*)(ws + OFF_KCC);
    ushort* xc   = (ushort*)(ws + OFF_XC);
    ushort* AFt  = (ushort*)(ws + OFF_AFT);
    ushort* P    = (ushort*)(ws + OFF_P);
    float*  FnT  = (float*)(ws + OFF_FNT);
    float*  AFp  = (float*)(ws + OFF_AFP);

    k_maskpool   <<<dim3(BATCH * N / 256), 256, 0, stream>>>(mask, m);
    k_scan       <<<dim3(BATCH), 256, 0, stream>>>(m, fgi, bgi, cnt, kmc, p2s);
    k_wconv      <<<dim3((CH * CIN + CH * KC) / 256), 256, 0, stream>>>(Kw, fw, Kwb, fwb);
    k_tr         <<<dim3(CH / 64, 64, BATCH), 256, 0, stream>>>(x, xT, CH);
    k_tr         <<<dim3(DVC / 64, 64, BATCH), 256, 0, stream>>>(dvt, dvtT, DVC);
    k_feats      <<<dim3(N / 128, CH / 64, BATCH), 128, 0, stream>>>(Kwb, xT, dvtT, Kb, FnT);
    k_padzero    <<<dim3(BATCH), 256, 0, stream>>>(cnt, Qc, Kcc);
    k_zero       <<<dim3(BATCH * N * 4 / 16 / 256), 256, 0, stream>>>((uint4*)vis);
    k_normalize  <<<dim3(BATCH * N / 4), 256, 0, stream>>>(FnT, p2s, Qc, Kcc);
    k_vgather    <<<dim3(BATCH * CH), 256, 0, stream>>>(x, bgi, cnt, xc);
    k_score      <<<dim3(N / 128, N / 128, BATCH), 256, 0, stream>>>(Qc, Kcc, kmc, cnt, P);
    k_rowsum     <<<dim3(BATCH * N / 4), 256, 0, stream>>>(P, cnt, inv);
    k_att_fore   <<<dim3(N / 128, CH / 64, BATCH * SPLITK), 128, 0, stream>>>(xc, P, cnt, AFp);
    k_afreduce   <<<dim3(BATCH * N / 4), 256, 0, stream>>>(AFp, inv, fgi, cnt, AFt);
    k_colsum     <<<dim3(2, QCH, BATCH), 256, 0, stream>>>(P, inv, cnt, part);
    k_colsum_final<<<dim3(BATCH * N / 256), 256, 0, stream>>>(part, bgi, cnt, vis);
    k_vismax     <<<dim3(1), 256, 0, stream>>>(vis, maxv);
    k_fused      <<<dim3(N / 128, CH / 64, BATCH), 128, 0, stream>>>(fwb, AFt, xT, x, m, out);
    k_attmask    <<<dim3(BATCH * 512 * 512 / 256), 256, 0, stream>>>(vis, maxv, out + (size_t)BATCH * CH * N);
}